// Round 15
// baseline (472.984 us; speedup 1.0000x reference)
//
#include <hip/hip_runtime.h>
#include <hip/hip_bf16.h>
#include <math.h>

#define FTS 256
#define IN_DIM 255
#define U0 512
#define U1 256
#define DIM 64
#define EMB 512
#define BATCH 256

typedef __attribute__((ext_vector_type(4))) float f32x4;
typedef _Float16 half8 __attribute__((ext_vector_type(8)));

__device__ __forceinline__ int swz8(int x) { return (x ^ (x >> 3)) & 7; }

// physical half-offset of logical col k in a pre-swizzled row r (64-half windows,
// 8-half chunks XOR'd by swz8(r)) — matches sgemm's LDS frag-read swizzle.
__device__ __forceinline__ int pswz(int k, int r) {
    return (k & ~63) | ((((k >> 3) & 7) ^ swz8(r)) << 3) | (k & 7);
}

// async 16B global->LDS copy; dst wave-uniform, lane lands at dst+lane*16
__device__ __forceinline__ void gload16(void* lds, const void* g) {
    __builtin_amdgcn_global_load_lds(
        (const __attribute__((address_space(1))) unsigned int*)g,
        (__attribute__((address_space(3))) unsigned int*)lds, 16, 0, 0);
}

// ---------------------------------------------------------------------------
// split_x: x [b][f][255] f32 -> Xh/Xl [f][b][256] fp16 pairs (lo*4096),
// zero-padded at k=255, pre-swizzled per row b.
// ---------------------------------------------------------------------------
__global__ __launch_bounds__(256)
void split_x(const float* __restrict__ x, _Float16* __restrict__ Xh,
             _Float16* __restrict__ Xl) {
    const int R = blockIdx.x * 4 + (threadIdx.x >> 6);  // R = f*256+b
    const int f = R >> 8, b = R & 255;
    const int kq = (threadIdx.x & 63) * 4;
    const float* src = x + ((size_t)b * FTS + f) * IN_DIM;
    _Float16 hb[4], lb[4];
#pragma unroll
    for (int i = 0; i < 4; i++) {
        int k = kq + i;
        float v = (k < IN_DIM) ? src[k] : 0.f;
        _Float16 h = (_Float16)v;
        hb[i] = h;
        lb[i] = (_Float16)((v - (float)h) * 4096.f);
    }
    size_t o = ((size_t)f * BATCH + b) * 256 + pswz(kq, b);
    *(uint2*)(Xh + o) = *(uint2*)hb;
    *(uint2*)(Xl + o) = *(uint2*)lb;
}

// ---------------------------------------------------------------------------
// cbk_prep: codebook [512][64] f32 -> fp16 splits (plain layout) + f64 norms
// ---------------------------------------------------------------------------
__global__ __launch_bounds__(256)
void cbk_prep(const float* __restrict__ cbk, _Float16* __restrict__ Ckh,
              _Float16* __restrict__ Ckl, float* __restrict__ cbn) {
    const int c = blockIdx.x * 256 + threadIdx.x;
    if (c >= EMB) return;
    const float* src = cbk + (size_t)c * 64;
    double s = 0.0;
#pragma unroll
    for (int i = 0; i < 8; i++) {
        float4 v0 = *(const float4*)(src + i * 8);
        float4 v1 = *(const float4*)(src + i * 8 + 4);
        float fv[8] = {v0.x, v0.y, v0.z, v0.w, v1.x, v1.y, v1.z, v1.w};
        _Float16 hv[8], lv[8];
#pragma unroll
        for (int e = 0; e < 8; e++) {
            float xx = fv[e];
            _Float16 hb = (_Float16)xx;
            hv[e] = hb;
            lv[e] = (_Float16)((xx - (float)hb) * 4096.f);
            s = fma((double)xx, (double)xx, s);
        }
        *(uint4*)(Ckh + (size_t)c * 64 + i * 8) = *(uint4*)hv;
        *(uint4*)(Ckl + (size_t)c * 64 + i * 8) = *(uint4*)lv;
    }
    cbn[c] = (float)s;
}

// ---------------------------------------------------------------------------
// sgemm: champion round-9 structure. LO=true: fp32-accurate fp16 2-split,
// 3 MFMAs/product, dual accumulator (encoder path — argmin-exact).
// LO=false: plain fp16, 1 MFMA/product, hi-halves only (decoder path).
// ---------------------------------------------------------------------------
template<int ACT, int BN, int NBX_LOG2, bool OUT_TRANS, bool SPLIT_OUT, bool LO>
__global__ __launch_bounds__(256)
void sgemm(const _Float16* __restrict__ Ah, const _Float16* __restrict__ Al,
           const float* __restrict__ W, const float* __restrict__ bias,
           float* __restrict__ Cf, _Float16* __restrict__ Ch, _Float16* __restrict__ Cl,
           int M, int K, int KW, int N) {
    constexpr int NB = BN / 32;               // n-frags per wave (4 or 2)
    constexpr int WR = (BN == 128) ? 8 : 4;   // W-prefetch float4 regs
    constexpr int BPF_LOG2 = NBX_LOG2 + 1;    // blocks per f (2 m-blocks)

    const int nwg = gridDim.x;
    const int bid = blockIdx.x;
    const int w   = (bid & 7) * (nwg >> 3) + (bid >> 3);
    const int f   = w >> BPF_LOG2;
    const int rem = w & ((1 << BPF_LOG2) - 1);
    const int bm  = (rem >> NBX_LOG2) * 128;
    const int bn  = (rem & ((1 << NBX_LOG2) - 1)) * BN;

    const int tid  = threadIdx.x;
    const int lane = tid & 63;
    const int wv   = tid >> 6;
    const int wr   = (wv >> 1) * 64;
    const int wc   = (wv & 1) * (BN / 2);
    const int kr   = lane & 15;
    const int kg   = lane >> 4;

    __shared__ _Float16 sAh[128 * 64];
    __shared__ _Float16 sAl[LO ? 128 * 64 : 8];
    __shared__ _Float16 sBh[BN * 64];
    __shared__ _Float16 sBl[LO ? BN * 64 : 8];

    f32x4 acc[4][NB] = {};
    f32x4 acx[4][NB] = {};

    const float* Wf = W + (size_t)f * KW * N;
    const _Float16* pAh = Ah + (size_t)f * M * K;
    const _Float16* pAl = LO ? Al + (size_t)f * M * K : nullptr;

    const int n0 = (BN == 128) ? (tid & 31) * 4 : (tid & 15) * 4;
    const int kb = (BN == 128) ? (tid >> 5) * 8 : (tid >> 4) * 4;
    float4 wreg[WR];

    auto stageA = [&](int k0) {
        if (LO) {
#pragma unroll
            for (int i = 0; i < 8; i++) {
                int gi = wv * 8 + i;                   // 32 groups of 8 rows
                const _Float16* base = (gi < 16) ? pAh : pAl;
                _Float16* dstb       = (gi < 16) ? sAh : sAl;
                int rowb = (gi & 15) * 8;
                const _Float16* src = base + (size_t)(bm + rowb + (lane >> 3)) * K
                                           + k0 + (lane & 7) * 8;
                gload16(dstb + rowb * 64, src);
            }
        } else {
#pragma unroll
            for (int i = 0; i < 4; i++) {
                int gi = wv * 4 + i;                   // 16 groups of 8 rows
                int rowb = gi * 8;
                const _Float16* src = pAh + (size_t)(bm + rowb + (lane >> 3)) * K
                                          + k0 + (lane & 7) * 8;
                gload16(sAh + rowb * 64, src);
            }
        }
    };
    auto loadW = [&](int k0) {
#pragma unroll
        for (int i = 0; i < WR; i++) {
            int k = k0 + kb + i;
            wreg[i] = (k < KW) ? *(const float4*)(Wf + (size_t)k * N + bn + n0)
                               : float4{0.f, 0.f, 0.f, 0.f};
        }
    };
    auto writeB = [&]() {
#pragma unroll
        for (int j = 0; j < 4; j++) {
            int n = n0 + j;
            _Float16 hv[WR], lv[WR];
#pragma unroll
            for (int i = 0; i < WR; i++) {
                float xx = ((const float*)&wreg[i])[j];
                _Float16 hb = (_Float16)xx;
                hv[i] = hb;
                if (LO) lv[i] = (_Float16)((xx - (float)hb) * 4096.f);
            }
            if (BN == 128) {
                int off = n * 64 + (((kb >> 3) ^ swz8(n)) << 3);
                *(uint4*)&sBh[off] = *(uint4*)hv;
                if (LO) *(uint4*)&sBl[off] = *(uint4*)lv;
            } else {
                int off = n * 64 + ((((kb >> 3) & 7) ^ swz8(n)) << 3) + (kb & 7);
                *(uint2*)&sBh[off] = *(uint2*)hv;
                if (LO) *(uint2*)&sBl[off] = *(uint2*)lv;
            }
        }
    };

    const int T = K / 64;

    // ---- prologue ----
    stageA(0);
    loadW(0);
    __syncthreads();          // drains gloads + W loads
    writeB();
    __syncthreads();          // B(0) visible

    for (int t = 0; t < T; t++) {
        const bool more = (t + 1 < T);
        if (more) loadW((t + 1) * 64);    // issue early: hides under MFMA burst

        // ---- compute current tile ----
#pragma unroll
        for (int kh = 0; kh < 2; kh++) {
            const int cb = kh * 4 + kg;
            half8 bh[NB], bl[NB];
#pragma unroll
            for (int nb = 0; nb < NB; nb++) {
                int n = wc + nb * 16 + kr;
                int off = n * 64 + ((cb ^ swz8(n)) << 3);
                bh[nb] = *(const half8*)&sBh[off];
                if (LO) bl[nb] = *(const half8*)&sBl[off];
            }
            __builtin_amdgcn_s_setprio(1);
#pragma unroll
            for (int rb = 0; rb < 4; rb++) {
                int m = wr + rb * 16 + kr;
                int off = m * 64 + ((cb ^ swz8(m)) << 3);
                half8 ah = *(const half8*)&sAh[off];
                half8 al;
                if (LO) al = *(const half8*)&sAl[off];
#pragma unroll
                for (int nb = 0; nb < NB; nb++) {
                    acc[rb][nb] = __builtin_amdgcn_mfma_f32_16x16x32_f16(ah, bh[nb], acc[rb][nb], 0, 0, 0);
                    if (LO) {
                        acx[rb][nb] = __builtin_amdgcn_mfma_f32_16x16x32_f16(ah, bl[nb], acx[rb][nb], 0, 0, 0);
                        acx[rb][nb] = __builtin_amdgcn_mfma_f32_16x16x32_f16(al, bh[nb], acx[rb][nb], 0, 0, 0);
                    }
                }
            }
            __builtin_amdgcn_s_setprio(0);
        }
        __syncthreads();                   // all readers done
        if (more) {
            stageA((t + 1) * 64);          // async gloads overwrite sA
            writeB();                      // prefetched W regs -> sB
            __syncthreads();               // drains gloads + ds_writes
        }
    }

    // ---- epilogue ----
#pragma unroll
    for (int nb = 0; nb < NB; nb++) {
        int col = bn + wc + nb * 16 + kr;
        float bval = bias[(size_t)f * N + col];
#pragma unroll
        for (int rb = 0; rb < 4; rb++) {
#pragma unroll
            for (int j = 0; j < 4; j++) {
                int row = bm + wr + rb * 16 + kg * 4 + j;
                float v = acc[rb][nb][j];
                if (LO) v += acx[rb][nb][j] * (1.0f / 4096.0f);
                v += bval;
                if (ACT == 0) v = v > 0.f ? v : 0.f;
                else          v = 1.f / (1.f + expf(-v));
                if (SPLIT_OUT) {
                    size_t o = ((size_t)f * M + row) * N + pswz(col, row);
                    _Float16 h = (_Float16)v;
                    Ch[o] = h;
                    if (LO) Cl[o] = (_Float16)((v - (float)h) * 4096.f);
                } else if (OUT_TRANS) {
                    Cf[(size_t)row * (FTS * FTS) + (size_t)f * N + col] = v;
                } else {
                    Cf[((size_t)f * M + row) * N + col] = v;
                }
            }
        }
    }
}

// ---------------------------------------------------------------------------
// VQ via fp16-split MFMA — barrier-free main loop. A-frags hoisted to regs
// after one staging barrier; codebook frags read directly from L2-resident
// split codebook (no LDS-B, no in-loop barriers). Numerics/order identical
// to the passing round-14 version.
// ---------------------------------------------------------------------------
__global__ __launch_bounds__(256)
void vq_mfma(const float* __restrict__ h, const _Float16* __restrict__ Ckh,
             const _Float16* __restrict__ Ckl, const float* __restrict__ cbn,
             _Float16* __restrict__ Qh) {
    __shared__ _Float16 sAh[128 * 64], sAl[128 * 64];
    __shared__ float bd_s[2][128];
    __shared__ int   bi_s[2][128];

    const int tid  = threadIdx.x;
    const int lane = tid & 63;
    const int wv   = tid >> 6;
    const int wr   = (wv >> 1) * 64;
    const int wch  = wv & 1;
    const int wc   = wch * 32;
    const int kr   = lane & 15;
    const int kg   = lane >> 4;
    const int r0   = blockIdx.x * 128;

    // stage h rows as fp16 hi/lo into LDS (swz8), one barrier
    {
        const int m  = tid >> 1;
        const int q2 = (tid & 1) * 32;
        const float* src = h + (size_t)(r0 + m) * 64 + q2;
        float fv[32];
#pragma unroll
        for (int i = 0; i < 8; i++)
            *(float4*)&fv[i * 4] = *(const float4*)(src + i * 4);
#pragma unroll
        for (int c2 = 0; c2 < 4; c2++) {
            _Float16 hv[8], lv[8];
#pragma unroll
            for (int e = 0; e < 8; e++) {
                float xx = fv[c2 * 8 + e];
                _Float16 hb = (_Float16)xx;
                hv[e] = hb;
                lv[e] = (_Float16)((xx - (float)hb) * 4096.f);
            }
            int dst = m * 64 + (((q2 >> 3) + c2) ^ swz8(m)) * 8;
            *(uint4*)&sAh[dst] = *(uint4*)hv;
            *(uint4*)&sAl[dst] = *(uint4*)lv;
        }
    }
    __syncthreads();

    // hoist this thread's A-frags into registers (reused across all 8 tiles)
    half8 ahr[2][4], alr[2][4];
#pragma unroll
    for (int kh = 0; kh < 2; kh++) {
        const int cb = kh * 4 + kg;
#pragma unroll
        for (int rb = 0; rb < 4; rb++) {
            int m = wr + rb * 16 + kr;
            int off = m * 64 + ((cb ^ swz8(m)) << 3);
            ahr[kh][rb] = *(const half8*)&sAh[off];
            alr[kh][rb] = *(const half8*)&sAl[off];
        }
    }

    float bestv[4][4];
    int   bestid[4][4];
#pragma unroll
    for (int rb = 0; rb < 4; rb++)
#pragma unroll
        for (int j = 0; j < 4; j++) { bestv[rb][j] = 3.4e38f; bestid[rb][j] = 0; }

    for (int ct = 0; ct < 8; ct++) {
        f32x4 acc[4][2] = {};
        f32x4 acx[4][2] = {};
#pragma unroll
        for (int kh = 0; kh < 2; kh++) {
            const int cb = kh * 4 + kg;
            half8 bh[2], bl[2];
#pragma unroll
            for (int nb = 0; nb < 2; nb++) {
                int code = ct * 64 + wc + nb * 16 + kr;
                bh[nb] = *(const half8*)(Ckh + (size_t)code * 64 + cb * 8);
                bl[nb] = *(const half8*)(Ckl + (size_t)code * 64 + cb * 8);
            }
#pragma unroll
            for (int rb = 0; rb < 4; rb++)
#pragma unroll
                for (int nb = 0; nb < 2; nb++) {
                    acc[rb][nb] = __builtin_amdgcn_mfma_f32_16x16x32_f16(ahr[kh][rb], bh[nb], acc[rb][nb], 0, 0, 0);
                    acx[rb][nb] = __builtin_amdgcn_mfma_f32_16x16x32_f16(ahr[kh][rb], bl[nb], acx[rb][nb], 0, 0, 0);
                    acx[rb][nb] = __builtin_amdgcn_mfma_f32_16x16x32_f16(alr[kh][rb], bh[nb], acx[rb][nb], 0, 0, 0);
                }
        }
        // per-tile argmin update (codes ascending: nb asc, strict <)
#pragma unroll
        for (int nb = 0; nb < 2; nb++) {
            int code = ct * 64 + wc + nb * 16 + kr;
            float cn = cbn[code];
#pragma unroll
            for (int rb = 0; rb < 4; rb++)
#pragma unroll
                for (int j = 0; j < 4; j++) {
                    float dot = acc[rb][nb][j] + acx[rb][nb][j] * (1.0f / 4096.0f);
                    float dist = fmaf(-2.f, dot, cn);
                    if (dist < bestv[rb][j]) { bestv[rb][j] = dist; bestid[rb][j] = code; }
                }
        }
    }

    // reduce across the 16 same-row lanes (low 4 bits)
#pragma unroll
    for (int rb = 0; rb < 4; rb++)
#pragma unroll
        for (int j = 0; j < 4; j++) {
#pragma unroll
            for (int mask = 1; mask < 16; mask <<= 1) {
                float od = __shfl_xor(bestv[rb][j], mask, 64);
                int   oi = __shfl_xor(bestid[rb][j], mask, 64);
                if (od < bestv[rb][j] || (od == bestv[rb][j] && oi < bestid[rb][j])) {
                    bestv[rb][j] = od; bestid[rb][j] = oi;
                }
            }
            if (kr == 0) {
                int row = wr + rb * 16 + kg * 4 + j;
                bd_s[wch][row] = bestv[rb][j];
                bi_s[wch][row] = bestid[rb][j];
            }
        }
    __syncthreads();

    if (tid < 128) {
        float d0 = bd_s[0][tid], d1 = bd_s[1][tid];
        int   i0 = bi_s[0][tid], i1 = bi_s[1][tid];
        bi_s[0][tid] = (d1 < d0 || (d1 == d0 && i1 < i0)) ? i1 : i0;
    }
    __syncthreads();

    // gather: write pre-swizzled hi-half q (plain fp16 decoder input)
    {
        const int r  = tid >> 1, hf = tid & 1;
        const int rg = r0 + r;
        const int idx = bi_s[0][r];
#pragma unroll
        for (int ci = 0; ci < 4; ci++) {
            int g  = hf * 4 + ci;
            int ph = (g ^ swz8(rg)) << 3;
            *(uint4*)&Qh[(size_t)rg * 64 + ph] = *(const uint4*)&Ckh[(size_t)idx * 64 + g * 8];
        }
    }
}

extern "C" void kernel_launch(void* const* d_in, const int* in_sizes, int n_in,
                              void* d_out, int out_size, void* d_ws, size_t ws_size,
                              hipStream_t stream) {
    const float* x   = (const float*)d_in[0];
    const float* w1  = (const float*)d_in[1];
    const float* b1  = (const float*)d_in[2];
    const float* w2  = (const float*)d_in[3];
    const float* b2  = (const float*)d_in[4];
    const float* w3  = (const float*)d_in[5];
    const float* b3  = (const float*)d_in[6];
    const float* cbk = (const float*)d_in[7];
    const float* w4  = (const float*)d_in[8];
    const float* b4  = (const float*)d_in[9];
    const float* w5  = (const float*)d_in[10];
    const float* b5  = (const float*)d_in[11];
    const float* w6  = (const float*)d_in[12];
    const float* b6  = (const float*)d_in[13];
    float* out = (float*)d_out;

    // ---- workspace overlay (~302 MiB) ----
    char* P = (char*)d_ws;
    _Float16* Xh  = (_Float16*)(P);                    // 32 MiB  [f][b][256]
    _Float16* Xl  = (_Float16*)(P + 33554432ull);
    _Float16* H1h = (_Float16*)(P + 67108864ull);      // 64 MiB  [f][b][512]
    _Float16* H1l = (_Float16*)(P + 134217728ull);
    _Float16* H2h = (_Float16*)(P + 201326592ull);     // 32 MiB  [f][b][256]
    _Float16* H2l = (_Float16*)(P + 234881024ull);
    float*    h3  = (float*)   (P + 268435456ull);     // 16 MiB  [f][b][64] f32
    _Float16* Qh  = (_Float16*)(P + 285212672ull);     // 8 MiB   [f][b][64]
    _Float16* Ckh = (_Float16*)(P + 301989888ull);     // 64 KiB
    _Float16* Ckl = (_Float16*)(P + 302055424ull);
    float*    cbn = (float*)   (P + 302120960ull);
    _Float16* Y1h = Xh;                                // X dead after L1
    _Float16* Y2h = H1h;                               // H1 dead after L2

    dim3 blk(256);

    split_x<<<dim3(16384), blk, 0, stream>>>(x, Xh, Xl);
    cbk_prep<<<dim3(2), blk, 0, stream>>>(cbk, Ckh, Ckl, cbn);

    // encoder: fp16 2-split, argmin-exact (LO=true)
    sgemm<0, 128, 2, false, true,  true ><<<dim3(2048), blk, 0, stream>>>(Xh,  Xl,  w1, b1, nullptr, H1h, H1l, BATCH, 256, IN_DIM, U0);
    sgemm<0, 128, 1, false, true,  true ><<<dim3(1024), blk, 0, stream>>>(H1h, H1l, w2, b2, nullptr, H2h, H2l, BATCH, U0,  U0,     U1);
    sgemm<0, 64,  0, false, false, true ><<<dim3(512),  blk, 0, stream>>>(H2h, H2l, w3, b3, h3,      nullptr, nullptr, BATCH, U1, U1, DIM);
    // vector quantization (exact fp16-split distances, barrier-free loop)
    vq_mfma<<<dim3(512), blk, 0, stream>>>(h3, Ckh, Ckl, cbn, Qh);
    // decoder: plain fp16, 1 MFMA/product (LO=false)
    sgemm<0, 128, 1, false, true,  false><<<dim3(1024), blk, 0, stream>>>(Qh,  nullptr, w4, b4, nullptr, Y1h, nullptr, BATCH, DIM, DIM, U1);
    sgemm<0, 128, 2, false, true,  false><<<dim3(2048), blk, 0, stream>>>(Y1h, nullptr, w5, b5, nullptr, Y2h, nullptr, BATCH, U1,  U1,  U0);
    sgemm<1, 128, 1, true,  false, false><<<dim3(1024), blk, 0, stream>>>(Y2h, nullptr, w6, b6, out,     nullptr, nullptr, BATCH, U0, U0, FTS);
}

// Round 16
// 446.042 us; speedup vs baseline: 1.0604x; 1.0604x over previous
//
#include <hip/hip_runtime.h>
#include <hip/hip_bf16.h>
#include <math.h>

#define FTS 256
#define IN_DIM 255
#define U0 512
#define U1 256
#define DIM 64
#define EMB 512
#define BATCH 256

typedef __attribute__((ext_vector_type(4))) float f32x4;
typedef _Float16 half8 __attribute__((ext_vector_type(8)));

__device__ __forceinline__ int swz8(int x) { return (x ^ (x >> 3)) & 7; }

// physical half-offset of logical col k in a pre-swizzled row r (64-half windows,
// 8-half chunks XOR'd by swz8(r)) — matches sgemm's LDS frag-read swizzle.
__device__ __forceinline__ int pswz(int k, int r) {
    return (k & ~63) | ((((k >> 3) & 7) ^ swz8(r)) << 3) | (k & 7);
}

// async 16B global->LDS copy; dst wave-uniform, lane lands at dst+lane*16
__device__ __forceinline__ void gload16(void* lds, const void* g) {
    __builtin_amdgcn_global_load_lds(
        (const __attribute__((address_space(1))) unsigned int*)g,
        (__attribute__((address_space(3))) unsigned int*)lds, 16, 0, 0);
}

// ---------------------------------------------------------------------------
// split_x: x [b][f][255] f32 -> Xh/Xl [f][b][256] fp16 pairs (lo*4096),
// zero-padded at k=255, pre-swizzled per row b.
// ---------------------------------------------------------------------------
__global__ __launch_bounds__(256)
void split_x(const float* __restrict__ x, _Float16* __restrict__ Xh,
             _Float16* __restrict__ Xl) {
    const int R = blockIdx.x * 4 + (threadIdx.x >> 6);  // R = f*256+b
    const int f = R >> 8, b = R & 255;
    const int kq = (threadIdx.x & 63) * 4;
    const float* src = x + ((size_t)b * FTS + f) * IN_DIM;
    _Float16 hb[4], lb[4];
#pragma unroll
    for (int i = 0; i < 4; i++) {
        int k = kq + i;
        float v = (k < IN_DIM) ? src[k] : 0.f;
        _Float16 h = (_Float16)v;
        hb[i] = h;
        lb[i] = (_Float16)((v - (float)h) * 4096.f);
    }
    size_t o = ((size_t)f * BATCH + b) * 256 + pswz(kq, b);
    *(uint2*)(Xh + o) = *(uint2*)hb;
    *(uint2*)(Xl + o) = *(uint2*)lb;
}

// ---------------------------------------------------------------------------
// cbk_prep: codebook [512][64] f32 -> fp16 splits (plain layout) + f64 norms
// ---------------------------------------------------------------------------
__global__ __launch_bounds__(256)
void cbk_prep(const float* __restrict__ cbk, _Float16* __restrict__ Ckh,
              _Float16* __restrict__ Ckl, float* __restrict__ cbn) {
    const int c = blockIdx.x * 256 + threadIdx.x;
    if (c >= EMB) return;
    const float* src = cbk + (size_t)c * 64;
    double s = 0.0;
#pragma unroll
    for (int i = 0; i < 8; i++) {
        float4 v0 = *(const float4*)(src + i * 8);
        float4 v1 = *(const float4*)(src + i * 8 + 4);
        float fv[8] = {v0.x, v0.y, v0.z, v0.w, v1.x, v1.y, v1.z, v1.w};
        _Float16 hv[8], lv[8];
#pragma unroll
        for (int e = 0; e < 8; e++) {
            float xx = fv[e];
            _Float16 hb = (_Float16)xx;
            hv[e] = hb;
            lv[e] = (_Float16)((xx - (float)hb) * 4096.f);
            s = fma((double)xx, (double)xx, s);
        }
        *(uint4*)(Ckh + (size_t)c * 64 + i * 8) = *(uint4*)hv;
        *(uint4*)(Ckl + (size_t)c * 64 + i * 8) = *(uint4*)lv;
    }
    cbn[c] = (float)s;
}

// ---------------------------------------------------------------------------
// sgemm: champion round-9 structure. LO=true: fp32-accurate fp16 2-split,
// 3 MFMAs/product, dual accumulator (encoder path — argmin-exact).
// LO=false: plain fp16, 1 MFMA/product, hi-halves only (decoder path).
// ---------------------------------------------------------------------------
template<int ACT, int BN, int NBX_LOG2, bool OUT_TRANS, bool SPLIT_OUT, bool LO>
__global__ __launch_bounds__(256)
void sgemm(const _Float16* __restrict__ Ah, const _Float16* __restrict__ Al,
           const float* __restrict__ W, const float* __restrict__ bias,
           float* __restrict__ Cf, _Float16* __restrict__ Ch, _Float16* __restrict__ Cl,
           int M, int K, int KW, int N) {
    constexpr int NB = BN / 32;               // n-frags per wave (4 or 2)
    constexpr int WR = (BN == 128) ? 8 : 4;   // W-prefetch float4 regs
    constexpr int BPF_LOG2 = NBX_LOG2 + 1;    // blocks per f (2 m-blocks)

    const int nwg = gridDim.x;
    const int bid = blockIdx.x;
    const int w   = (bid & 7) * (nwg >> 3) + (bid >> 3);
    const int f   = w >> BPF_LOG2;
    const int rem = w & ((1 << BPF_LOG2) - 1);
    const int bm  = (rem >> NBX_LOG2) * 128;
    const int bn  = (rem & ((1 << NBX_LOG2) - 1)) * BN;

    const int tid  = threadIdx.x;
    const int lane = tid & 63;
    const int wv   = tid >> 6;
    const int wr   = (wv >> 1) * 64;
    const int wc   = (wv & 1) * (BN / 2);
    const int kr   = lane & 15;
    const int kg   = lane >> 4;

    __shared__ _Float16 sAh[128 * 64];
    __shared__ _Float16 sAl[LO ? 128 * 64 : 8];
    __shared__ _Float16 sBh[BN * 64];
    __shared__ _Float16 sBl[LO ? BN * 64 : 8];

    f32x4 acc[4][NB] = {};
    f32x4 acx[4][NB] = {};

    const float* Wf = W + (size_t)f * KW * N;
    const _Float16* pAh = Ah + (size_t)f * M * K;
    const _Float16* pAl = LO ? Al + (size_t)f * M * K : nullptr;

    const int n0 = (BN == 128) ? (tid & 31) * 4 : (tid & 15) * 4;
    const int kb = (BN == 128) ? (tid >> 5) * 8 : (tid >> 4) * 4;
    float4 wreg[WR];

    auto stageA = [&](int k0) {
        if (LO) {
#pragma unroll
            for (int i = 0; i < 8; i++) {
                int gi = wv * 8 + i;                   // 32 groups of 8 rows
                const _Float16* base = (gi < 16) ? pAh : pAl;
                _Float16* dstb       = (gi < 16) ? sAh : sAl;
                int rowb = (gi & 15) * 8;
                const _Float16* src = base + (size_t)(bm + rowb + (lane >> 3)) * K
                                           + k0 + (lane & 7) * 8;
                gload16(dstb + rowb * 64, src);
            }
        } else {
#pragma unroll
            for (int i = 0; i < 4; i++) {
                int gi = wv * 4 + i;                   // 16 groups of 8 rows
                int rowb = gi * 8;
                const _Float16* src = pAh + (size_t)(bm + rowb + (lane >> 3)) * K
                                          + k0 + (lane & 7) * 8;
                gload16(sAh + rowb * 64, src);
            }
        }
    };
    auto loadW = [&](int k0) {
#pragma unroll
        for (int i = 0; i < WR; i++) {
            int k = k0 + kb + i;
            wreg[i] = (k < KW) ? *(const float4*)(Wf + (size_t)k * N + bn + n0)
                               : float4{0.f, 0.f, 0.f, 0.f};
        }
    };
    auto writeB = [&]() {
#pragma unroll
        for (int j = 0; j < 4; j++) {
            int n = n0 + j;
            _Float16 hv[WR], lv[WR];
#pragma unroll
            for (int i = 0; i < WR; i++) {
                float xx = ((const float*)&wreg[i])[j];
                _Float16 hb = (_Float16)xx;
                hv[i] = hb;
                if (LO) lv[i] = (_Float16)((xx - (float)hb) * 4096.f);
            }
            if (BN == 128) {
                int off = n * 64 + (((kb >> 3) ^ swz8(n)) << 3);
                *(uint4*)&sBh[off] = *(uint4*)hv;
                if (LO) *(uint4*)&sBl[off] = *(uint4*)lv;
            } else {
                int off = n * 64 + ((((kb >> 3) & 7) ^ swz8(n)) << 3) + (kb & 7);
                *(uint2*)&sBh[off] = *(uint2*)hv;
                if (LO) *(uint2*)&sBl[off] = *(uint2*)lv;
            }
        }
    };

    const int T = K / 64;

    // ---- prologue ----
    stageA(0);
    loadW(0);
    __syncthreads();          // drains gloads + W loads
    writeB();
    __syncthreads();          // B(0) visible

    for (int t = 0; t < T; t++) {
        const bool more = (t + 1 < T);
        if (more) loadW((t + 1) * 64);    // issue early: hides under MFMA burst

        // ---- compute current tile ----
#pragma unroll
        for (int kh = 0; kh < 2; kh++) {
            const int cb = kh * 4 + kg;
            half8 bh[NB], bl[NB];
#pragma unroll
            for (int nb = 0; nb < NB; nb++) {
                int n = wc + nb * 16 + kr;
                int off = n * 64 + ((cb ^ swz8(n)) << 3);
                bh[nb] = *(const half8*)&sBh[off];
                if (LO) bl[nb] = *(const half8*)&sBl[off];
            }
            __builtin_amdgcn_s_setprio(1);
#pragma unroll
            for (int rb = 0; rb < 4; rb++) {
                int m = wr + rb * 16 + kr;
                int off = m * 64 + ((cb ^ swz8(m)) << 3);
                half8 ah = *(const half8*)&sAh[off];
                half8 al;
                if (LO) al = *(const half8*)&sAl[off];
#pragma unroll
                for (int nb = 0; nb < NB; nb++) {
                    acc[rb][nb] = __builtin_amdgcn_mfma_f32_16x16x32_f16(ah, bh[nb], acc[rb][nb], 0, 0, 0);
                    if (LO) {
                        acx[rb][nb] = __builtin_amdgcn_mfma_f32_16x16x32_f16(ah, bl[nb], acx[rb][nb], 0, 0, 0);
                        acx[rb][nb] = __builtin_amdgcn_mfma_f32_16x16x32_f16(al, bh[nb], acx[rb][nb], 0, 0, 0);
                    }
                }
            }
            __builtin_amdgcn_s_setprio(0);
        }
        __syncthreads();                   // all readers done
        if (more) {
            stageA((t + 1) * 64);          // async gloads overwrite sA
            writeB();                      // prefetched W regs -> sB
            __syncthreads();               // drains gloads + ds_writes
        }
    }

    // ---- epilogue ----
#pragma unroll
    for (int nb = 0; nb < NB; nb++) {
        int col = bn + wc + nb * 16 + kr;
        float bval = bias[(size_t)f * N + col];
#pragma unroll
        for (int rb = 0; rb < 4; rb++) {
#pragma unroll
            for (int j = 0; j < 4; j++) {
                int row = bm + wr + rb * 16 + kg * 4 + j;
                float v = acc[rb][nb][j];
                if (LO) v += acx[rb][nb][j] * (1.0f / 4096.0f);
                v += bval;
                if (ACT == 0) v = v > 0.f ? v : 0.f;
                else          v = 1.f / (1.f + expf(-v));
                if (SPLIT_OUT) {
                    size_t o = ((size_t)f * M + row) * N + pswz(col, row);
                    _Float16 h = (_Float16)v;
                    Ch[o] = h;
                    if (LO) Cl[o] = (_Float16)((v - (float)h) * 4096.f);
                } else if (OUT_TRANS) {
                    Cf[(size_t)row * (FTS * FTS) + (size_t)f * N + col] = v;
                } else {
                    Cf[((size_t)f * M + row) * N + col] = v;
                }
            }
        }
    }
}

// ---------------------------------------------------------------------------
// l3_vq: FUSED layer-3 GEMM (fp16 2-split, BN=64, argmin-exact) + VQ.
// L3 block (f, bm) computes h3 rows f*256+bm..+128 — exactly one VQ tile.
// Epilogue converts acc straight into the swz8 LDS h-tile (same f32 values,
// same split math as the old global round-trip); VQ ct-loop/reduce/gather
// are byte-for-byte the round-14 passing code.
// ---------------------------------------------------------------------------
__global__ __launch_bounds__(256)
void l3_vq(const _Float16* __restrict__ Ah, const _Float16* __restrict__ Al,
           const float* __restrict__ W, const float* __restrict__ bias,
           const _Float16* __restrict__ Ckh, const _Float16* __restrict__ Ckl,
           const float* __restrict__ cbn, _Float16* __restrict__ Qh) {
    const int nwg = gridDim.x;       // 512
    const int bid = blockIdx.x;
    const int w   = (bid & 7) * (nwg >> 3) + (bid >> 3);
    const int f   = w >> 1;
    const int bm  = (w & 1) * 128;

    const int tid  = threadIdx.x;
    const int lane = tid & 63;
    const int wv   = tid >> 6;
    const int wr   = (wv >> 1) * 64;
    const int wch  = wv & 1;
    const int wc   = wch * 32;
    const int kr   = lane & 15;
    const int kg   = lane >> 4;

    __shared__ _Float16 sAh[128 * 64], sAl[128 * 64];   // A tile, then h tile
    __shared__ _Float16 sBh[64 * 64],  sBl[64 * 64];    // W tile, then cbk tile
    __shared__ float bd_s[2][128];
    __shared__ int   bi_s[2][128];

    f32x4 acc[4][2] = {};
    f32x4 acx[4][2] = {};

    const float* Wf = W + (size_t)f * U1 * DIM;
    const _Float16* pAh = Ah + (size_t)f * BATCH * U1;
    const _Float16* pAl = Al + (size_t)f * BATCH * U1;

    const int n0 = (tid & 15) * 4;
    const int kb = (tid >> 4) * 4;
    float4 wreg[4];

    auto stageA = [&](int k0) {
#pragma unroll
        for (int i = 0; i < 8; i++) {
            int gi = wv * 8 + i;
            const _Float16* base = (gi < 16) ? pAh : pAl;
            _Float16* dstb       = (gi < 16) ? sAh : sAl;
            int rowb = (gi & 15) * 8;
            const _Float16* src = base + (size_t)(bm + rowb + (lane >> 3)) * U1
                                       + k0 + (lane & 7) * 8;
            gload16(dstb + rowb * 64, src);
        }
    };
    auto loadW = [&](int k0) {
#pragma unroll
        for (int i = 0; i < 4; i++)
            wreg[i] = *(const float4*)(Wf + (size_t)(k0 + kb + i) * DIM + n0);
    };
    auto writeB = [&]() {
#pragma unroll
        for (int j = 0; j < 4; j++) {
            int n = n0 + j;
            _Float16 hv[4], lv[4];
#pragma unroll
            for (int i = 0; i < 4; i++) {
                float xx = ((const float*)&wreg[i])[j];
                _Float16 hb = (_Float16)xx;
                hv[i] = hb;
                lv[i] = (_Float16)((xx - (float)hb) * 4096.f);
            }
            int off = n * 64 + ((((kb >> 3) & 7) ^ swz8(n)) << 3) + (kb & 7);
            *(uint2*)&sBh[off] = *(uint2*)hv;
            *(uint2*)&sBl[off] = *(uint2*)lv;
        }
    };

    // ---- GEMM: prologue + K-loop (T = 4) ----
    stageA(0);
    loadW(0);
    __syncthreads();
    writeB();
    __syncthreads();

    for (int t = 0; t < 4; t++) {
        const bool more = (t + 1 < 4);
        if (more) loadW((t + 1) * 64);
#pragma unroll
        for (int kh = 0; kh < 2; kh++) {
            const int cb = kh * 4 + kg;
            half8 bh[2], bl[2];
#pragma unroll
            for (int nb = 0; nb < 2; nb++) {
                int n = wc + nb * 16 + kr;
                int off = n * 64 + ((cb ^ swz8(n)) << 3);
                bh[nb] = *(const half8*)&sBh[off];
                bl[nb] = *(const half8*)&sBl[off];
            }
            __builtin_amdgcn_s_setprio(1);
#pragma unroll
            for (int rb = 0; rb < 4; rb++) {
                int m = wr + rb * 16 + kr;
                int off = m * 64 + ((cb ^ swz8(m)) << 3);
                half8 ah = *(const half8*)&sAh[off];
                half8 al = *(const half8*)&sAl[off];
#pragma unroll
                for (int nb = 0; nb < 2; nb++) {
                    acc[rb][nb] = __builtin_amdgcn_mfma_f32_16x16x32_f16(ah, bh[nb], acc[rb][nb], 0, 0, 0);
                    acx[rb][nb] = __builtin_amdgcn_mfma_f32_16x16x32_f16(ah, bl[nb], acx[rb][nb], 0, 0, 0);
                    acx[rb][nb] = __builtin_amdgcn_mfma_f32_16x16x32_f16(al, bh[nb], acx[rb][nb], 0, 0, 0);
                }
            }
            __builtin_amdgcn_s_setprio(0);
        }
        __syncthreads();                  // all sA/sB reads of tile t done
        if (more) {
            stageA((t + 1) * 64);
            writeB();
            __syncthreads();
        }
    }

    // ---- fused epilogue: h3 values -> fp16 split tile in LDS (swz8) ----
#pragma unroll
    for (int nb = 0; nb < 2; nb++) {
        int col = wc + nb * 16 + kr;
        float bval = bias[(size_t)f * DIM + col];
#pragma unroll
        for (int rb = 0; rb < 4; rb++) {
#pragma unroll
            for (int j = 0; j < 4; j++) {
                int row = wr + rb * 16 + kg * 4 + j;   // local row 0..127
                float v = acc[rb][nb][j] + acx[rb][nb][j] * (1.0f / 4096.0f) + bval;
                v = v > 0.f ? v : 0.f;
                _Float16 h = (_Float16)v;
                int off = row * 64 + ((((col >> 3) & 7) ^ swz8(row)) << 3) + (col & 7);
                sAh[off] = h;
                sAl[off] = (_Float16)((v - (float)h) * 4096.f);
            }
        }
    }

    // ---- VQ (round-14 internals) ----
    float bestv[4][4];
    int   bestid[4][4];
#pragma unroll
    for (int rb = 0; rb < 4; rb++)
#pragma unroll
        for (int j = 0; j < 4; j++) { bestv[rb][j] = 3.4e38f; bestid[rb][j] = 0; }

    for (int ct = 0; ct < 8; ct++) {
        __syncthreads();
        {
            const int c  = tid >> 2;
            const int kq = (tid & 3) * 16;
            const _Float16* s1 = Ckh + (size_t)(ct * 64 + c) * 64 + kq;
            const _Float16* s2 = Ckl + (size_t)(ct * 64 + c) * 64 + kq;
#pragma unroll
            for (int i = 0; i < 2; i++) {
                int dst = c * 64 + (((kq >> 3) + i) ^ swz8(c)) * 8;
                *(uint4*)&sBh[dst] = *(const uint4*)(s1 + i * 8);
                *(uint4*)&sBl[dst] = *(const uint4*)(s2 + i * 8);
            }
        }
        __syncthreads();

        f32x4 vacc[4][2] = {};
        f32x4 vacx[4][2] = {};
#pragma unroll
        for (int kh = 0; kh < 2; kh++) {
            const int cb = kh * 4 + kg;
            half8 ah[4], al[4], bh[2], bl[2];
#pragma unroll
            for (int rb = 0; rb < 4; rb++) {
                int m = wr + rb * 16 + kr;
                int off = m * 64 + (cb ^ swz8(m)) * 8;
                ah[rb] = *(const half8*)&sAh[off];
                al[rb] = *(const half8*)&sAl[off];
            }
#pragma unroll
            for (int nb = 0; nb < 2; nb++) {
                int n = wc + nb * 16 + kr;
                int off = n * 64 + (cb ^ swz8(n)) * 8;
                bh[nb] = *(const half8*)&sBh[off];
                bl[nb] = *(const half8*)&sBl[off];
            }
#pragma unroll
            for (int rb = 0; rb < 4; rb++)
#pragma unroll
                for (int nb = 0; nb < 2; nb++) {
                    vacc[rb][nb] = __builtin_amdgcn_mfma_f32_16x16x32_f16(ah[rb], bh[nb], vacc[rb][nb], 0, 0, 0);
                    vacx[rb][nb] = __builtin_amdgcn_mfma_f32_16x16x32_f16(ah[rb], bl[nb], vacx[rb][nb], 0, 0, 0);
                    vacx[rb][nb] = __builtin_amdgcn_mfma_f32_16x16x32_f16(al[rb], bh[nb], vacx[rb][nb], 0, 0, 0);
                }
        }
#pragma unroll
        for (int nb = 0; nb < 2; nb++) {
            int code = ct * 64 + wc + nb * 16 + kr;
            float cn = cbn[code];
#pragma unroll
            for (int rb = 0; rb < 4; rb++)
#pragma unroll
                for (int j = 0; j < 4; j++) {
                    float dot = vacc[rb][nb][j] + vacx[rb][nb][j] * (1.0f / 4096.0f);
                    float dist = fmaf(-2.f, dot, cn);
                    if (dist < bestv[rb][j]) { bestv[rb][j] = dist; bestid[rb][j] = code; }
                }
        }
    }

#pragma unroll
    for (int rb = 0; rb < 4; rb++)
#pragma unroll
        for (int j = 0; j < 4; j++) {
#pragma unroll
            for (int mask = 1; mask < 16; mask <<= 1) {
                float od = __shfl_xor(bestv[rb][j], mask, 64);
                int   oi = __shfl_xor(bestid[rb][j], mask, 64);
                if (od < bestv[rb][j] || (od == bestv[rb][j] && oi < bestid[rb][j])) {
                    bestv[rb][j] = od; bestid[rb][j] = oi;
                }
            }
            if (kr == 0) {
                int row = wr + rb * 16 + kg * 4 + j;
                bd_s[wch][row] = bestv[rb][j];
                bi_s[wch][row] = bestid[rb][j];
            }
        }
    __syncthreads();

    if (tid < 128) {
        float d0 = bd_s[0][tid], d1 = bd_s[1][tid];
        int   i0 = bi_s[0][tid], i1 = bi_s[1][tid];
        bi_s[0][tid] = (d1 < d0 || (d1 == d0 && i1 < i0)) ? i1 : i0;
    }
    __syncthreads();

    // gather: write pre-swizzled hi-half q (plain fp16 decoder input)
    {
        const int r  = tid >> 1, hf = tid & 1;
        const int b  = bm + r;                 // row within f panel
        const int idx = bi_s[0][r];
#pragma unroll
        for (int ci = 0; ci < 4; ci++) {
            int g  = hf * 4 + ci;
            int ph = (g ^ swz8(b)) << 3;
            *(uint4*)&Qh[((size_t)f * BATCH + b) * 64 + ph] =
                *(const uint4*)&Ckh[(size_t)idx * 64 + g * 8];
        }
    }
}

extern "C" void kernel_launch(void* const* d_in, const int* in_sizes, int n_in,
                              void* d_out, int out_size, void* d_ws, size_t ws_size,
                              hipStream_t stream) {
    const float* x   = (const float*)d_in[0];
    const float* w1  = (const float*)d_in[1];
    const float* b1  = (const float*)d_in[2];
    const float* w2  = (const float*)d_in[3];
    const float* b2  = (const float*)d_in[4];
    const float* w3  = (const float*)d_in[5];
    const float* b3  = (const float*)d_in[6];
    const float* cbk = (const float*)d_in[7];
    const float* w4  = (const float*)d_in[8];
    const float* b4  = (const float*)d_in[9];
    const float* w5  = (const float*)d_in[10];
    const float* b5  = (const float*)d_in[11];
    const float* w6  = (const float*)d_in[12];
    const float* b6  = (const float*)d_in[13];
    float* out = (float*)d_out;

    // ---- workspace overlay (~302 MiB) ----
    char* P = (char*)d_ws;
    _Float16* Xh  = (_Float16*)(P);                    // 32 MiB  [f][b][256]
    _Float16* Xl  = (_Float16*)(P + 33554432ull);
    _Float16* H1h = (_Float16*)(P + 67108864ull);      // 64 MiB  [f][b][512]
    _Float16* H1l = (_Float16*)(P + 134217728ull);
    _Float16* H2h = (_Float16*)(P + 201326592ull);     // 32 MiB  [f][b][256]
    _Float16* H2l = (_Float16*)(P + 234881024ull);
    _Float16* Qh  = (_Float16*)(P + 285212672ull);     // 8 MiB   [f][b][64]
    _Float16* Ckh = (_Float16*)(P + 301989888ull);     // 64 KiB
    _Float16* Ckl = (_Float16*)(P + 302055424ull);
    float*    cbn = (float*)   (P + 302120960ull);
    _Float16* Y1h = Xh;                                // X dead after L1
    _Float16* Y2h = H1h;                               // H1 dead after L2

    dim3 blk(256);

    split_x<<<dim3(16384), blk, 0, stream>>>(x, Xh, Xl);
    cbk_prep<<<dim3(2), blk, 0, stream>>>(cbk, Ckh, Ckl, cbn);

    // encoder: fp16 2-split, argmin-exact (LO=true)
    sgemm<0, 128, 2, false, true,  true ><<<dim3(2048), blk, 0, stream>>>(Xh,  Xl,  w1, b1, nullptr, H1h, H1l, BATCH, 256, IN_DIM, U0);
    sgemm<0, 128, 1, false, true,  true ><<<dim3(1024), blk, 0, stream>>>(H1h, H1l, w2, b2, nullptr, H2h, H2l, BATCH, U0,  U0,     U1);
    // fused layer-3 + vector quantization (exact fp16-split distances)
    l3_vq<<<dim3(512), blk, 0, stream>>>(H2h, H2l, w3, b3, Ckh, Ckl, cbn, Qh);
    // decoder: plain fp16, 1 MFMA/product (LO=false)
    sgemm<0, 128, 1, false, true,  false><<<dim3(1024), blk, 0, stream>>>(Qh,  nullptr, w4, b4, nullptr, Y1h, nullptr, BATCH, DIM, DIM, U1);
    sgemm<0, 128, 2, false, true,  false><<<dim3(2048), blk, 0, stream>>>(Y1h, nullptr, w5, b5, nullptr, Y2h, nullptr, BATCH, U1,  U1,  U0);
    sgemm<1, 128, 1, true,  false, false><<<dim3(1024), blk, 0, stream>>>(Y2h, nullptr, w6, b6, out,     nullptr, nullptr, BATCH, U0, U0, FTS);
}